// Round 6
// baseline (356.731 us; speedup 1.0000x reference)
//
#include <hip/hip_runtime.h>
#include <hip/hip_bf16.h>
#include <math.h>
#include <stdint.h>

typedef unsigned short u16;
typedef __attribute__((ext_vector_type(8))) short bf8;    // 8 bf16 raw bits (4 VGPRs)
typedef __attribute__((ext_vector_type(4))) float f4;     // 16x16 MFMA C/D frag
typedef __attribute__((ext_vector_type(16))) float f16v;  // 32x32 MFMA C/D frag

#define SC_LOG2E 0.09016844f   // 256^-0.5 * log2(e)

__device__ __forceinline__ float b2f(u16 u) {
    union { uint32_t i; float f; } v; v.i = ((uint32_t)u) << 16; return v.f;
}
__device__ __forceinline__ u16 f2b(float f) {
    union { float f; uint32_t i; } v; v.f = f;
    uint32_t r = (v.i + 0x7FFFu + ((v.i >> 16) & 1u)) >> 16;
    return (u16)r;
}

// ---------------------------------------------------------------------------
// Kernel 0: weight prep (f32 -> bf16, transposed).
// ---------------------------------------------------------------------------
__global__ __launch_bounds__(256) void prep_weights(
        const float* __restrict__ Wqkv, const float* __restrict__ Wgate,
        const float* __restrict__ Wproj,
        u16* __restrict__ WT_all, u16* __restrict__ WTp) {
    int e = blockIdx.x * 256 + threadIdx.x;
    if (e < 262144) {
        int n = e >> 8, k = e & 255;
        WT_all[e] = f2b((n < 768) ? Wqkv[k * 768 + n] : Wgate[k * 256 + (n - 768)]);
    } else {
        int e2 = e - 262144;
        int n = e2 >> 8, k = e2 & 255;
        WTp[e2] = f2b(Wproj[k * 256 + n]);
    }
}

// ---------------------------------------------------------------------------
// Kernel 1: fused GEMM  y = x @ [W_qkv | W_gate]  (M=16384, N=1024, K=256)
// ---------------------------------------------------------------------------
__global__ __launch_bounds__(512) void gemm_qkvz(
        const float* __restrict__ x, const u16* __restrict__ WT,
        const float* __restrict__ b_gate,
        u16* __restrict__ qo, u16* __restrict__ ko,
        u16* __restrict__ vT, u16* __restrict__ zo) {
    __shared__ u16 As[128][72];
    __shared__ u16 Bs[256][72];
    const int t = threadIdx.x;
    const int w = t >> 6, lane = t & 63, l15 = lane & 15, q4 = lane >> 4;
    const int m0 = blockIdx.x * 128;
    const int n0 = blockIdx.y * 256;

    f4 acc[16];
#pragma unroll
    for (int i = 0; i < 16; i++) acc[i] = (f4){0.f, 0.f, 0.f, 0.f};

    for (int kt = 0; kt < 4; ++kt) {
        __syncthreads();
#pragma unroll
        for (int p = 0; p < 2; p++) {   // A tile: 128x64, f32 -> bf16
            int r = p * 64 + (t >> 3), cg = (t & 7) * 8;
            const float* xs = &x[(m0 + r) * 256 + kt * 64 + cg];
            float4 f0 = *(const float4*)xs;
            float4 f1 = *(const float4*)(xs + 4);
            u16 tmp[8];
            tmp[0] = f2b(f0.x); tmp[1] = f2b(f0.y);
            tmp[2] = f2b(f0.z); tmp[3] = f2b(f0.w);
            tmp[4] = f2b(f1.x); tmp[5] = f2b(f1.y);
            tmp[6] = f2b(f1.z); tmp[7] = f2b(f1.w);
            *(bf8*)&As[r][cg] = *(bf8*)tmp;
        }
#pragma unroll
        for (int p = 0; p < 4; p++) {   // B tile: 256(n) x 64(k)
            int nr = p * 64 + (t >> 3), cg = (t & 7) * 8;
            *(bf8*)&Bs[nr][cg] = *(const bf8*)&WT[(n0 + nr) * 256 + kt * 64 + cg];
        }
        __syncthreads();
#pragma unroll
        for (int c = 0; c < 2; c++) {
            bf8 af = *(bf8*)&As[w * 16 + l15][c * 32 + q4 * 8];
#pragma unroll
            for (int nt = 0; nt < 16; nt++) {
                bf8 bf = *(bf8*)&Bs[nt * 16 + l15][c * 32 + q4 * 8];
                acc[nt] = __builtin_amdgcn_mfma_f32_16x16x32_bf16(af, bf, acc[nt], 0, 0, 0);
            }
        }
    }

    const int rb = m0 + w * 16 + q4 * 4;
    if (blockIdx.y == 0) {
#pragma unroll
        for (int nt = 0; nt < 16; nt++) {
            int col = nt * 16 + l15;
#pragma unroll
            for (int r = 0; r < 4; r++) qo[(rb + r) * 256 + col] = f2b(acc[nt][r]);
        }
    } else if (blockIdx.y == 1) {
#pragma unroll
        for (int nt = 0; nt < 16; nt++) {
            int col = nt * 16 + l15;
#pragma unroll
            for (int r = 0; r < 4; r++) ko[(rb + r) * 256 + col] = f2b(acc[nt][r]);
        }
    } else if (blockIdx.y == 2) {          // v transposed: vT[b][c][n]
        int bb = rb >> 12, nn = rb & 4095;
#pragma unroll
        for (int nt = 0; nt < 16; nt++) {
            int vc = nt * 16 + l15;
            ushort4 pk;
            pk.x = f2b(acc[nt][0]); pk.y = f2b(acc[nt][1]);
            pk.z = f2b(acc[nt][2]); pk.w = f2b(acc[nt][3]);
            *(ushort4*)&vT[(bb * 256 + vc) * 4096 + nn] = pk;
        }
    } else {                               // z = gelu_exact(y + b_gate)
#pragma unroll
        for (int nt = 0; nt < 16; nt++) {
            int gc = nt * 16 + l15;
            float bg = b_gate[gc];
#pragma unroll
            for (int r = 0; r < 4; r++) {
                float v = acc[nt][r] + bg;
                float g = 0.5f * v * (1.0f + erff(v * 0.70710678118654752f));
                zo[(rb + r) * 256 + gc] = f2b(g);
            }
        }
    }
}

// ---------------------------------------------------------------------------
// Kernel 2: depthwise 3x3 conv PE, sliding-window (3 loads/pixel).
// ---------------------------------------------------------------------------
__global__ __launch_bounds__(256) void conv_pe(
        const u16* __restrict__ q, const float* __restrict__ pw,
        const float* __restrict__ pb, u16* __restrict__ pe) {
    const int b = blockIdx.x >> 6, h = blockIdx.x & 63;
    const int c = threadIdx.x;
    float wgt[9];
#pragma unroll
    for (int i = 0; i < 9; i++) wgt[i] = pw[c * 9 + i];
    const float bias = pb[c];
    const u16* qb = q + b * (4096 * 256);
    u16* peb = pe + b * (4096 * 256);
    const bool vTop = h > 0, vBot = h < 63;
    const u16* rT = qb + (h - 1) * 64 * 256 + c;
    const u16* rM = qb + h * 64 * 256 + c;
    const u16* rB = qb + (h + 1) * 64 * 256 + c;

    float t0 = 0.f, t1, t2, m0v = 0.f, m1, m2, b0 = 0.f, b1, b2v;
    t1 = vTop ? b2f(rT[0]) : 0.f;
    m1 = b2f(rM[0]);
    b1 = vBot ? b2f(rB[0]) : 0.f;
    for (int w2 = 0; w2 < 64; ++w2) {
        if (w2 < 63) {
            int o = (w2 + 1) * 256;
            t2 = vTop ? b2f(rT[o]) : 0.f;
            m2 = b2f(rM[o]);
            b2v = vBot ? b2f(rB[o]) : 0.f;
        } else { t2 = 0.f; m2 = 0.f; b2v = 0.f; }
        float acc = bias
            + wgt[0] * t0 + wgt[1] * t1 + wgt[2] * t2
            + wgt[3] * m0v + wgt[4] * m1 + wgt[5] * m2
            + wgt[6] * b0 + wgt[7] * b1 + wgt[8] * b2v;
        peb[(h * 64 + w2) * 256 + c] = f2b(acc);
        t0 = t1; t1 = t2; m0v = m1; m1 = m2; b0 = b1; b1 = b2v;
    }
}

// ---------------------------------------------------------------------------
// Kernel 3: flash attention, 32x32x16 MFMA, no-max softmax.
// Grid 256 = 64 qtiles x 4 batches (b=bid&3). 512 thr / 8 waves, 1 block/CU.
// Wave (kg=w>>1, qg=w&1). qf = one 32-q-row group as B-frags (64 VGPRs),
// loaded from LDS which is then OVERWRITTEN by K staging -> compiler must
// keep qf in registers (LDS reloads across barriers+writes are illegal).
// Per iter (128 keys): K staged to LDS via global_load_lds w/ XOR chunk
// swizzle; QK wave -> one 32key x 32q C-tile (16 MFMA); P -> LDS [q][key];
// PV: V direct from global, wave -> 2 vc-groups x 32q (16 MFMA).
// l accumulated per-lane from exps (1 shfl/iter).
// ---------------------------------------------------------------------------
__global__ __launch_bounds__(512) void attn(
        const u16* __restrict__ q, const u16* __restrict__ k,
        const u16* __restrict__ vT, const u16* __restrict__ pe,
        const u16* __restrict__ z, u16* __restrict__ u) {
    __shared__ u16 KsLin[128 * 256];   // 64KB: K tile, rows swizzled by 16B chunk
    __shared__ u16 Ps[64][136];        // P [q][key], pad 8
    __shared__ float l_part[8][64];

    const int t = threadIdx.x;
    const int w = t >> 6, lane = t & 63;
    const int i = lane & 31, h = lane >> 5;
    const int kg = w >> 1, qg = w & 1;
    const int b = blockIdx.x & 3, qt = blockIdx.x >> 2;
    const int m0 = b * 4096 + qt * 64;

    const u16* kb = k + (size_t)b * 4096 * 256;
    const u16* vb = vT + (size_t)b * 256 * 4096;

    // ---- stage Q tile (64x256) into KsLin with chunk-XOR swizzle ----
#pragma unroll
    for (int cc = 0; cc < 4; cc++) {
        int row = t >> 3;
        int c = (t & 7) + cc * 8;            // 16B chunk 0..31
        *(bf8*)&KsLin[row * 256 + ((c ^ (row & 31)) << 3)] =
            *(const bf8*)&q[(size_t)(m0 + row) * 256 + (c << 3)];
    }
    __syncthreads();

    // ---- qf: B-frags for this wave's q-group (16 frags = 64 VGPRs) ----
    bf8 qf[16];
#pragma unroll
    for (int g = 0; g < 16; g++) {
        int cidx = (g * 2 + h) ^ i;
        qf[g] = *(bf8*)&KsLin[(qg * 32 + i) * 256 + (cidx << 3)];
    }
    __syncthreads();   // all qf reads done before K staging overwrites

    // ---- K staging via global_load_lds (16B, swizzled source) ----
    auto stageK = [&](int kt2) {
        const int k0s = kt2 * 128;
#pragma unroll
        for (int r = 0; r < 8; r++) {
            int base_row = w * 16 + r * 2;
            int row = base_row + (lane >> 5);
            const u16* gsrc = kb + (size_t)(k0s + row) * 256
                              + (((lane & 31) ^ (row & 31)) << 3);
            u16* ldst = &KsLin[base_row * 256];     // wave-uniform base
            __builtin_amdgcn_global_load_lds(
                (const __attribute__((address_space(1))) unsigned int*)gsrc,
                (__attribute__((address_space(3))) unsigned int*)ldst, 16, 0, 0);
        }
    };
    stageK(0);

    f16v O[2];
#pragma unroll
    for (int tt = 0; tt < 2; tt++)
#pragma unroll
        for (int e = 0; e < 16; e++) O[tt][e] = 0.f;
    float lrow = 0.f;

    for (int kt = 0; kt < 32; ++kt) {
        const int k0 = kt * 128;
        __syncthreads();   // staging drained (vmcnt) + prev PV done

        // ---- QK: C[key 32][q 32] for (kg, qg), K=256 over 16 MFMAs ----
        f16v St;
#pragma unroll
        for (int e = 0; e < 16; e++) St[e] = 0.f;
#pragma unroll
        for (int g = 0; g < 16; g++) {
            int cidx = (g * 2 + h) ^ i;
            bf8 kf = *(bf8*)&KsLin[(kg * 32 + i) * 256 + (cidx << 3)];
            St = __builtin_amdgcn_mfma_f32_32x32x16_bf16(kf, qf[g], St, 0, 0, 0);
        }

        // ---- P = exp(S*scale) -> Ps[q][key] (b64 packed); lrow accum ----
        float psum = 0.f;
#pragma unroll
        for (int rr = 0; rr < 4; rr++) {
            float e0 = exp2f(fminf(fmaxf(St[rr * 4 + 0] * SC_LOG2E, -30.f), 30.f));
            float e1 = exp2f(fminf(fmaxf(St[rr * 4 + 1] * SC_LOG2E, -30.f), 30.f));
            float e2 = exp2f(fminf(fmaxf(St[rr * 4 + 2] * SC_LOG2E, -30.f), 30.f));
            float e3 = exp2f(fminf(fmaxf(St[rr * 4 + 3] * SC_LOG2E, -30.f), 30.f));
            ushort4 pk;
            pk.x = f2b(e0); pk.y = f2b(e1); pk.z = f2b(e2); pk.w = f2b(e3);
            *(ushort4*)&Ps[qg * 32 + i][kg * 32 + rr * 8 + h * 4] = pk;
            psum += (e0 + e1) + (e2 + e3);
        }
        psum += __shfl_xor(psum, 32);
        lrow += psum;
        __syncthreads();   // P ready, Ks fully consumed

        if (kt < 31) stageK(kt + 1);   // overlaps PV below

        // ---- PV: O^T[vc][q], wave covers vc groups {kg*?}: w>>1 and +4 ----
        bf8 pf[8];
#pragma unroll
        for (int kk = 0; kk < 8; kk++)
            pf[kk] = *(bf8*)&Ps[qg * 32 + i][kk * 16 + h * 8];
#pragma unroll
        for (int tt = 0; tt < 2; tt++) {
            const int vcg = (w >> 1) + tt * 4;
            bf8 vf[8];
#pragma unroll
            for (int kk = 0; kk < 8; kk++)
                vf[kk] = *(const bf8*)&vb[(size_t)(vcg * 32 + i) * 4096
                                          + k0 + kk * 16 + h * 8];
#pragma unroll
            for (int kk = 0; kk < 8; kk++)
                O[tt] = __builtin_amdgcn_mfma_f32_32x32x16_bf16(vf[kk], pf[kk], O[tt], 0, 0, 0);
        }
    }

    if (h == 0) l_part[w][qg * 32 + i] = lrow;
    __syncthreads();

    // ---- epilogue: u = (O/l + pe) * z -> bf16 ----
    const int qrow = qg * 32 + i;
    const float lt = l_part[qg][qrow] + l_part[2 + qg][qrow]
                   + l_part[4 + qg][qrow] + l_part[6 + qg][qrow];
    const float linv = 1.0f / lt;
    const size_t mrow = (size_t)(m0 + qrow) * 256;
#pragma unroll
    for (int tt = 0; tt < 2; tt++) {
        const int vcg = (w >> 1) + tt * 4;
#pragma unroll
        for (int rr = 0; rr < 4; rr++) {
            int vcb = vcg * 32 + rr * 8 + h * 4;
            ushort4 pe4 = *(const ushort4*)&pe[mrow + vcb];
            ushort4 z4  = *(const ushort4*)&z[mrow + vcb];
            ushort4 o4;
            o4.x = f2b((O[tt][rr * 4 + 0] * linv + b2f(pe4.x)) * b2f(z4.x));
            o4.y = f2b((O[tt][rr * 4 + 1] * linv + b2f(pe4.y)) * b2f(z4.y));
            o4.z = f2b((O[tt][rr * 4 + 2] * linv + b2f(pe4.z)) * b2f(z4.z));
            o4.w = f2b((O[tt][rr * 4 + 3] * linv + b2f(pe4.w)) * b2f(z4.w));
            *(ushort4*)&u[mrow + vcb] = o4;
        }
    }
}

// ---------------------------------------------------------------------------
// Kernel 4: out = u @ W_proj   (M=16384, N=256, K=256). f32 output.
// ---------------------------------------------------------------------------
__global__ __launch_bounds__(256) void gemm_proj(
        const u16* __restrict__ u, const u16* __restrict__ WTp,
        float* __restrict__ out) {
    __shared__ u16 As[64][72];
    __shared__ u16 Bs[256][72];
    const int t = threadIdx.x;
    const int w = t >> 6, lane = t & 63, l15 = lane & 15, q4 = lane >> 4;
    const int m0 = blockIdx.x * 64;

    f4 acc[16];
#pragma unroll
    for (int i = 0; i < 16; i++) acc[i] = (f4){0.f, 0.f, 0.f, 0.f};

    for (int kt = 0; kt < 4; ++kt) {
        __syncthreads();
#pragma unroll
        for (int p = 0; p < 2; p++) {
            int r = p * 32 + (t >> 3), cg = (t & 7) * 8;
            *(bf8*)&As[r][cg] = *(const bf8*)&u[(m0 + r) * 256 + kt * 64 + cg];
        }
#pragma unroll
        for (int p = 0; p < 8; p++) {
            int nr = p * 32 + (t >> 3), cg = (t & 7) * 8;
            *(bf8*)&Bs[nr][cg] = *(const bf8*)&WTp[nr * 256 + kt * 64 + cg];
        }
        __syncthreads();
#pragma unroll
        for (int c = 0; c < 2; c++) {
            bf8 af = *(bf8*)&As[w * 16 + l15][c * 32 + q4 * 8];
#pragma unroll
            for (int nt = 0; nt < 16; nt++) {
                bf8 bf = *(bf8*)&Bs[nt * 16 + l15][c * 32 + q4 * 8];
                acc[nt] = __builtin_amdgcn_mfma_f32_16x16x32_bf16(af, bf, acc[nt], 0, 0, 0);
            }
        }
    }
    const int rb = m0 + w * 16 + q4 * 4;
#pragma unroll
    for (int nt = 0; nt < 16; nt++) {
        int col = nt * 16 + l15;
#pragma unroll
        for (int r = 0; r < 4; r++) out[(rb + r) * 256 + col] = acc[nt][r];
    }
}

// ---------------------------------------------------------------------------
extern "C" void kernel_launch(void* const* d_in, const int* in_sizes, int n_in,
                              void* d_out, int out_size, void* d_ws, size_t ws_size,
                              hipStream_t stream) {
    (void)in_sizes; (void)n_in; (void)out_size; (void)ws_size;
    const float* x      = (const float*)d_in[0];
    const float* Wqkv   = (const float*)d_in[1];
    const float* Wgate  = (const float*)d_in[2];
    const float* bgate  = (const float*)d_in[3];
    const float* Wproj  = (const float*)d_in[4];
    const float* pw     = (const float*)d_in[5];
    const float* pb     = (const float*)d_in[6];
    float* out = (float*)d_out;

    char* ws = (char*)d_ws;
    u16* WT_all = (u16*)(ws);                   // 524288 B
    u16* WTp    = (u16*)(ws + 524288);          // 131072 B
    u16* q      = (u16*)(ws + 655360);          // 8388608
    u16* k      = (u16*)(ws + 9043968);         // 8388608
    u16* vT     = (u16*)(ws + 17432576);        // 8388608
    u16* z      = (u16*)(ws + 25821184);        // 8388608
    u16* pe     = (u16*)(ws + 34209792);        // 8388608
    u16* u      = (u16*)(ws + 42598400);        // 8388608

    prep_weights<<<1280, 256, 0, stream>>>(Wqkv, Wgate, Wproj, WT_all, WTp);
    gemm_qkvz<<<dim3(128, 4), 512, 0, stream>>>(x, WT_all, bgate, q, k, vT, z);
    conv_pe<<<256, 256, 0, stream>>>(q, pw, pb, pe);
    attn<<<256, 512, 0, stream>>>(q, k, vT, pe, z, u);
    gemm_proj<<<256, 256, 0, stream>>>(u, WTp, out);
}

// Round 7
// 299.836 us; speedup vs baseline: 1.1898x; 1.1898x over previous
//
#include <hip/hip_runtime.h>
#include <hip/hip_bf16.h>
#include <math.h>
#include <stdint.h>

typedef unsigned short u16;
typedef __attribute__((ext_vector_type(8))) short bf8;    // 8 bf16 raw bits (4 VGPRs)
typedef __attribute__((ext_vector_type(4))) float f4;     // 16x16 MFMA C/D frag

#define SC_LOG2E 0.09016844f   // 256^-0.5 * log2(e)

__device__ __forceinline__ float b2f(u16 u) {
    union { uint32_t i; float f; } v; v.i = ((uint32_t)u) << 16; return v.f;
}
__device__ __forceinline__ u16 f2b(float f) {
    union { float f; uint32_t i; } v; v.f = f;
    uint32_t r = (v.i + 0x7FFFu + ((v.i >> 16) & 1u)) >> 16;
    return (u16)r;
}

// ---------------------------------------------------------------------------
// Kernel 0: weight prep (f32 -> bf16, transposed).
// ---------------------------------------------------------------------------
__global__ __launch_bounds__(256) void prep_weights(
        const float* __restrict__ Wqkv, const float* __restrict__ Wgate,
        const float* __restrict__ Wproj,
        u16* __restrict__ WT_all, u16* __restrict__ WTp) {
    int e = blockIdx.x * 256 + threadIdx.x;
    if (e < 262144) {
        int n = e >> 8, k = e & 255;
        WT_all[e] = f2b((n < 768) ? Wqkv[k * 768 + n] : Wgate[k * 256 + (n - 768)]);
    } else {
        int e2 = e - 262144;
        int n = e2 >> 8, k = e2 & 255;
        WTp[e2] = f2b(Wproj[k * 256 + n]);
    }
}

// ---------------------------------------------------------------------------
// Kernel 1: fused GEMM  y = x @ [W_qkv | W_gate]  (M=16384, N=1024, K=256)
// ---------------------------------------------------------------------------
__global__ __launch_bounds__(512) void gemm_qkvz(
        const float* __restrict__ x, const u16* __restrict__ WT,
        const float* __restrict__ b_gate,
        u16* __restrict__ qo, u16* __restrict__ ko,
        u16* __restrict__ vT, u16* __restrict__ zo) {
    __shared__ u16 As[128][72];
    __shared__ u16 Bs[256][72];
    const int t = threadIdx.x;
    const int w = t >> 6, lane = t & 63, l15 = lane & 15, q4 = lane >> 4;
    const int m0 = blockIdx.x * 128;
    const int n0 = blockIdx.y * 256;

    f4 acc[16];
#pragma unroll
    for (int i = 0; i < 16; i++) acc[i] = (f4){0.f, 0.f, 0.f, 0.f};

    for (int kt = 0; kt < 4; ++kt) {
        __syncthreads();
#pragma unroll
        for (int p = 0; p < 2; p++) {   // A tile: 128x64, f32 -> bf16
            int r = p * 64 + (t >> 3), cg = (t & 7) * 8;
            const float* xs = &x[(m0 + r) * 256 + kt * 64 + cg];
            float4 f0 = *(const float4*)xs;
            float4 f1 = *(const float4*)(xs + 4);
            u16 tmp[8];
            tmp[0] = f2b(f0.x); tmp[1] = f2b(f0.y);
            tmp[2] = f2b(f0.z); tmp[3] = f2b(f0.w);
            tmp[4] = f2b(f1.x); tmp[5] = f2b(f1.y);
            tmp[6] = f2b(f1.z); tmp[7] = f2b(f1.w);
            *(bf8*)&As[r][cg] = *(bf8*)tmp;
        }
#pragma unroll
        for (int p = 0; p < 4; p++) {   // B tile: 256(n) x 64(k)
            int nr = p * 64 + (t >> 3), cg = (t & 7) * 8;
            *(bf8*)&Bs[nr][cg] = *(const bf8*)&WT[(n0 + nr) * 256 + kt * 64 + cg];
        }
        __syncthreads();
#pragma unroll
        for (int c = 0; c < 2; c++) {
            bf8 af = *(bf8*)&As[w * 16 + l15][c * 32 + q4 * 8];
#pragma unroll
            for (int nt = 0; nt < 16; nt++) {
                bf8 bf = *(bf8*)&Bs[nt * 16 + l15][c * 32 + q4 * 8];
                acc[nt] = __builtin_amdgcn_mfma_f32_16x16x32_bf16(af, bf, acc[nt], 0, 0, 0);
            }
        }
    }

    const int rb = m0 + w * 16 + q4 * 4;
    if (blockIdx.y == 0) {
#pragma unroll
        for (int nt = 0; nt < 16; nt++) {
            int col = nt * 16 + l15;
#pragma unroll
            for (int r = 0; r < 4; r++) qo[(rb + r) * 256 + col] = f2b(acc[nt][r]);
        }
    } else if (blockIdx.y == 1) {
#pragma unroll
        for (int nt = 0; nt < 16; nt++) {
            int col = nt * 16 + l15;
#pragma unroll
            for (int r = 0; r < 4; r++) ko[(rb + r) * 256 + col] = f2b(acc[nt][r]);
        }
    } else if (blockIdx.y == 2) {          // v transposed: vT[b][c][n]
        int bb = rb >> 12, nn = rb & 4095;
#pragma unroll
        for (int nt = 0; nt < 16; nt++) {
            int vc = nt * 16 + l15;
            ushort4 pk;
            pk.x = f2b(acc[nt][0]); pk.y = f2b(acc[nt][1]);
            pk.z = f2b(acc[nt][2]); pk.w = f2b(acc[nt][3]);
            *(ushort4*)&vT[(bb * 256 + vc) * 4096 + nn] = pk;
        }
    } else {                               // z = gelu_exact(y + b_gate)
#pragma unroll
        for (int nt = 0; nt < 16; nt++) {
            int gc = nt * 16 + l15;
            float bg = b_gate[gc];
#pragma unroll
            for (int r = 0; r < 4; r++) {
                float v = acc[nt][r] + bg;
                float g = 0.5f * v * (1.0f + erff(v * 0.70710678118654752f));
                zo[(rb + r) * 256 + gc] = f2b(g);
            }
        }
    }
}

// ---------------------------------------------------------------------------
// Kernel 2: depthwise 3x3 conv PE, sliding-window (3 loads/pixel).
// ---------------------------------------------------------------------------
__global__ __launch_bounds__(256) void conv_pe(
        const u16* __restrict__ q, const float* __restrict__ pw,
        const float* __restrict__ pb, u16* __restrict__ pe) {
    const int b = blockIdx.x >> 6, h = blockIdx.x & 63;
    const int c = threadIdx.x;
    float wgt[9];
#pragma unroll
    for (int i = 0; i < 9; i++) wgt[i] = pw[c * 9 + i];
    const float bias = pb[c];
    const u16* qb = q + b * (4096 * 256);
    u16* peb = pe + b * (4096 * 256);
    const bool vTop = h > 0, vBot = h < 63;
    const u16* rT = qb + (h - 1) * 64 * 256 + c;
    const u16* rM = qb + h * 64 * 256 + c;
    const u16* rB = qb + (h + 1) * 64 * 256 + c;

    float t0 = 0.f, t1, t2, m0v = 0.f, m1, m2, b0 = 0.f, b1, b2v;
    t1 = vTop ? b2f(rT[0]) : 0.f;
    m1 = b2f(rM[0]);
    b1 = vBot ? b2f(rB[0]) : 0.f;
    for (int w2 = 0; w2 < 64; ++w2) {
        if (w2 < 63) {
            int o = (w2 + 1) * 256;
            t2 = vTop ? b2f(rT[o]) : 0.f;
            m2 = b2f(rM[o]);
            b2v = vBot ? b2f(rB[o]) : 0.f;
        } else { t2 = 0.f; m2 = 0.f; b2v = 0.f; }
        float acc = bias
            + wgt[0] * t0 + wgt[1] * t1 + wgt[2] * t2
            + wgt[3] * m0v + wgt[4] * m1 + wgt[5] * m2
            + wgt[6] * b0 + wgt[7] * b1 + wgt[8] * b2v;
        peb[(h * 64 + w2) * 256 + c] = f2b(acc);
        t0 = t1; t1 = t2; m0v = m1; m1 = m2; b0 = b1; b1 = b2v;
    }
}

// ---------------------------------------------------------------------------
// Kernel 3: flash attention v7. Qt=64, Kt=64, grid 256 (=64 qt x 4 batches,
// b=bid&3 -> one batch per XCD). 512 thr / 8 waves.
// COALESCED staging: K & Q via global_load_lds (16B, rows contiguous; LDS
// layout padded per 2-row PAIR, stride 1040B, since glb_lds dest is
// wave-uniform+lane*16 and one wave-issue = exactly one pair). V via
// VGPR->ds_write_b128 into 144B-row tile (global: 8 lanes = 128B contig).
// All LDS frag reads <=2-way banked. Pipeline per iter: top-barrier (drains
// prefetch) -> ds_write V -> QK(16 MFMA/wave) -> exp/P->LDS -> mid-barrier
// -> issue K[kt+1] glb_lds + V[kt+1] global loads -> PV(16 MFMA/wave).
// Staging flies across PV and drains at next top-barrier.
// Waves: QK (kg=w>>1 key16-stripe, qh=w&1 q-half); PV (vc-stripe 32*w).
// ---------------------------------------------------------------------------
__global__ __launch_bounds__(512) void attn(
        const u16* __restrict__ q, const u16* __restrict__ k,
        const u16* __restrict__ vT, const u16* __restrict__ pe,
        const u16* __restrict__ z, u16* __restrict__ u) {
    __shared__ u16 Kst[32 * 520];      // 64 rows x 256, pair-1040B layout
    __shared__ u16 Vs[256 * 72];       // [vc][64 keys + 8 pad]
    __shared__ u16 Ps[64 * 72];        // [q][64 keys + 8 pad]
    __shared__ float l_part[8][64];

    const int t = threadIdx.x;
    const int w = t >> 6, lane = t & 63, l15 = lane & 15, q4 = lane >> 4;
    const int kg = w >> 1, qh = w & 1;
    const int b = blockIdx.x & 3, qt = blockIdx.x >> 2;
    const int m0 = b * 4096 + qt * 64;

    const u16* kb = k + (size_t)b * 4096 * 256;
    const u16* vb = vT + (size_t)b * 256 * 4096;

    const int rowme = t >> 5;          // 0..15 (row within 16-row round)
    const int chme = t & 31;           // 16B chunk within 512B row

    // stage 64 rows x 256 cols from src (row-major) into Kst (pair-1040)
    auto stage64 = [&](const u16* src) {
#pragma unroll
        for (int rr = 0; rr < 4; rr++) {
            const u16* g = src + (size_t)(rr * 16 + rowme) * 256 + chme * 8;
            u16* l = &Kst[(rr * 8 + w) * 520];
            __builtin_amdgcn_global_load_lds(
                (const __attribute__((address_space(1))) unsigned int*)g,
                (__attribute__((address_space(3))) unsigned int*)l, 16, 0, 0);
        }
    };
    // Kst element address for (row, 16B-chunk cn)
    auto kaddr = [&](int row, int cn) -> u16* {
        return &Kst[(row >> 1) * 520 + (row & 1) * 256 + cn * 8];
    };

    // ---- prologue: stage Q into Kst, read resident qf, then K[0]/V[0] ----
    stage64(q + (size_t)m0 * 256);
    __syncthreads();
    bf8 qf[2][8];
#pragma unroll
    for (int qtt = 0; qtt < 2; qtt++)
#pragma unroll
        for (int c = 0; c < 8; c++)
            qf[qtt][c] = *(bf8*)kaddr(qh * 32 + qtt * 16 + l15, c * 4 + q4);
    __syncthreads();                   // all qf reads done before K overwrites

    stage64(kb);                       // K[0]
    bf8 vreg[4];
    {
        const int vcb = t >> 3, ch = t & 7;
#pragma unroll
        for (int j = 0; j < 4; j++)
            vreg[j] = *(const bf8*)&vb[(size_t)(j * 64 + vcb) * 4096 + ch * 8];
    }

    f4 O[2][4];
#pragma unroll
    for (int vg = 0; vg < 2; vg++)
#pragma unroll
        for (int qg = 0; qg < 4; qg++) O[vg][qg] = (f4){0.f, 0.f, 0.f, 0.f};
    float lrow[2] = {0.f, 0.f};

    for (int kt = 0; kt < 64; ++kt) {
        __syncthreads();               // drains K[kt] glb_lds + V[kt] globals

        // ---- commit V[kt] regs -> Vs ----
        {
            const int vcb = t >> 3, ch = t & 7;
#pragma unroll
            for (int j = 0; j < 4; j++)
                *(bf8*)&Vs[(size_t)(j * 64 + vcb) * 72 + ch * 8] = vreg[j];
        }

        // ---- QK: C[key16 (kg)][q16] x2 q-tiles, K=256 ----
        f4 St[2];
        St[0] = (f4){0.f, 0.f, 0.f, 0.f};
        St[1] = (f4){0.f, 0.f, 0.f, 0.f};
#pragma unroll
        for (int c = 0; c < 8; c++) {
            bf8 kf = *(bf8*)kaddr(kg * 16 + l15, c * 4 + q4);
            St[0] = __builtin_amdgcn_mfma_f32_16x16x32_bf16(kf, qf[0][c], St[0], 0, 0, 0);
            St[1] = __builtin_amdgcn_mfma_f32_16x16x32_bf16(kf, qf[1][c], St[1], 0, 0, 0);
        }

        // ---- P = exp(S*scale) -> Ps[q][key]; l accumulated ----
#pragma unroll
        for (int qtt = 0; qtt < 2; qtt++) {
            float e0 = exp2f(fminf(fmaxf(St[qtt][0] * SC_LOG2E, -30.f), 30.f));
            float e1 = exp2f(fminf(fmaxf(St[qtt][1] * SC_LOG2E, -30.f), 30.f));
            float e2 = exp2f(fminf(fmaxf(St[qtt][2] * SC_LOG2E, -30.f), 30.f));
            float e3 = exp2f(fminf(fmaxf(St[qtt][3] * SC_LOG2E, -30.f), 30.f));
            ushort4 pk;
            pk.x = f2b(e0); pk.y = f2b(e1); pk.z = f2b(e2); pk.w = f2b(e3);
            int qrow = qh * 32 + qtt * 16 + l15;
            *(ushort4*)&Ps[qrow * 72 + kg * 16 + q4 * 4] = pk;
            float s = (e0 + e1) + (e2 + e3);
            s += __shfl_xor(s, 16);
            s += __shfl_xor(s, 32);
            lrow[qtt] += s;
        }
        __syncthreads();               // P visible; Kst reads done; Vs ready

        // ---- prefetch next tile (overlaps PV, drains at next top-barrier) --
        if (kt < 63) {
            stage64(kb + (size_t)(kt + 1) * 64 * 256);
            const int vcb = t >> 3, ch = t & 7;
#pragma unroll
            for (int j = 0; j < 4; j++)
                vreg[j] = *(const bf8*)&vb[(size_t)(j * 64 + vcb) * 4096
                                           + (kt + 1) * 64 + ch * 8];
        }

        // ---- PV: wave vc-stripe [32w,32w+32); O[vc][q] += V^T P ----
        bf8 pf[4][2], vfr[2][2];
#pragma unroll
        for (int qg = 0; qg < 4; qg++)
#pragma unroll
            for (int kh = 0; kh < 2; kh++)
                pf[qg][kh] = *(bf8*)&Ps[(qg * 16 + l15) * 72 + kh * 32 + q4 * 8];
#pragma unroll
        for (int vg = 0; vg < 2; vg++)
#pragma unroll
            for (int kh = 0; kh < 2; kh++)
                vfr[vg][kh] = *(bf8*)&Vs[(w * 32 + vg * 16 + l15) * 72 + kh * 32 + q4 * 8];
#pragma unroll
        for (int vg = 0; vg < 2; vg++)
#pragma unroll
            for (int qg = 0; qg < 4; qg++) {
                O[vg][qg] = __builtin_amdgcn_mfma_f32_16x16x32_bf16(
                    vfr[vg][0], pf[qg][0], O[vg][qg], 0, 0, 0);
                O[vg][qg] = __builtin_amdgcn_mfma_f32_16x16x32_bf16(
                    vfr[vg][1], pf[qg][1], O[vg][qg], 0, 0, 0);
            }
    }

    if (q4 == 0) {
        l_part[w][qh * 32 + l15] = lrow[0];
        l_part[w][qh * 32 + 16 + l15] = lrow[1];
    }
    __syncthreads();

    // ---- epilogue: u = (O/l + pe) * z -> bf16 ----
#pragma unroll
    for (int qg = 0; qg < 4; qg++) {
        int qrow = qg * 16 + l15;
        int qhq = qg >> 1;
        float lt = l_part[qhq][qrow] + l_part[2 + qhq][qrow]
                 + l_part[4 + qhq][qrow] + l_part[6 + qhq][qrow];
        float linv = 1.0f / lt;
        size_t mrow = (size_t)(m0 + qrow) * 256;
#pragma unroll
        for (int vg = 0; vg < 2; vg++) {
            int vcb = w * 32 + vg * 16 + q4 * 4;
            ushort4 pe4 = *(const ushort4*)&pe[mrow + vcb];
            ushort4 z4  = *(const ushort4*)&z[mrow + vcb];
            ushort4 o4;
            o4.x = f2b((O[vg][qg][0] * linv + b2f(pe4.x)) * b2f(z4.x));
            o4.y = f2b((O[vg][qg][1] * linv + b2f(pe4.y)) * b2f(z4.y));
            o4.z = f2b((O[vg][qg][2] * linv + b2f(pe4.z)) * b2f(z4.z));
            o4.w = f2b((O[vg][qg][3] * linv + b2f(pe4.w)) * b2f(z4.w));
            *(ushort4*)&u[mrow + vcb] = o4;
        }
    }
}

// ---------------------------------------------------------------------------
// Kernel 4: out = u @ W_proj   (M=16384, N=256, K=256). f32 output.
// ---------------------------------------------------------------------------
__global__ __launch_bounds__(256) void gemm_proj(
        const u16* __restrict__ u, const u16* __restrict__ WTp,
        float* __restrict__ out) {
    __shared__ u16 As[64][72];
    __shared__ u16 Bs[256][72];
    const int t = threadIdx.x;
    const int w = t >> 6, lane = t & 63, l15 = lane & 15, q4 = lane >> 4;
    const int m0 = blockIdx.x * 64;

    f4 acc[16];
#pragma unroll
    for (int i = 0; i < 16; i++) acc[i] = (f4){0.f, 0.f, 0.f, 0.f};

    for (int kt = 0; kt < 4; ++kt) {
        __syncthreads();
#pragma unroll
        for (int p = 0; p < 2; p++) {
            int r = p * 32 + (t >> 3), cg = (t & 7) * 8;
            *(bf8*)&As[r][cg] = *(const bf8*)&u[(m0 + r) * 256 + kt * 64 + cg];
        }
#pragma unroll
        for (int p = 0; p < 8; p++) {
            int nr = p * 32 + (t >> 3), cg = (t & 7) * 8;
            *(bf8*)&Bs[nr][cg] = *(const bf8*)&WTp[nr * 256 + kt * 64 + cg];
        }
        __syncthreads();
#pragma unroll
        for (int c = 0; c < 2; c++) {
            bf8 af = *(bf8*)&As[w * 16 + l15][c * 32 + q4 * 8];
#pragma unroll
            for (int nt = 0; nt < 16; nt++) {
                bf8 bf = *(bf8*)&Bs[nt * 16 + l15][c * 32 + q4 * 8];
                acc[nt] = __builtin_amdgcn_mfma_f32_16x16x32_bf16(af, bf, acc[nt], 0, 0, 0);
            }
        }
    }
    const int rb = m0 + w * 16 + q4 * 4;
#pragma unroll
    for (int nt = 0; nt < 16; nt++) {
        int col = nt * 16 + l15;
#pragma unroll
        for (int r = 0; r < 4; r++) out[(rb + r) * 256 + col] = acc[nt][r];
    }
}

// ---------------------------------------------------------------------------
extern "C" void kernel_launch(void* const* d_in, const int* in_sizes, int n_in,
                              void* d_out, int out_size, void* d_ws, size_t ws_size,
                              hipStream_t stream) {
    (void)in_sizes; (void)n_in; (void)out_size; (void)ws_size;
    const float* x      = (const float*)d_in[0];
    const float* Wqkv   = (const float*)d_in[1];
    const float* Wgate  = (const float*)d_in[2];
    const float* bgate  = (const float*)d_in[3];
    const float* Wproj  = (const float*)d_in[4];
    const float* pw     = (const float*)d_in[5];
    const float* pb     = (const float*)d_in[6];
    float* out = (float*)d_out;

    char* ws = (char*)d_ws;
    u16* WT_all = (u16*)(ws);                   // 524288 B
    u16* WTp    = (u16*)(ws + 524288);          // 131072 B
    u16* q      = (u16*)(ws + 655360);          // 8388608
    u16* k      = (u16*)(ws + 9043968);         // 8388608
    u16* vT     = (u16*)(ws + 17432576);        // 8388608
    u16* z      = (u16*)(ws + 25821184);        // 8388608
    u16* pe     = (u16*)(ws + 34209792);        // 8388608
    u16* u      = (u16*)(ws + 42598400);        // 8388608

    prep_weights<<<1280, 256, 0, stream>>>(Wqkv, Wgate, Wproj, WT_all, WTp);
    gemm_qkvz<<<dim3(128, 4), 512, 0, stream>>>(x, WT_all, bgate, q, k, vT, z);
    conv_pe<<<256, 256, 0, stream>>>(q, pw, pb, pe);
    attn<<<256, 512, 0, stream>>>(q, k, vT, pe, z, u);
    gemm_proj<<<256, 256, 0, stream>>>(u, WTp, out);
}